// Round 10
// baseline (288.395 us; speedup 1.0000x reference)
//
#include <hip/hip_runtime.h>
#include <hip/hip_bf16.h>

#define BIGV 1.0e9f

static constexpr int B_ = 32;
static constexpr int L_ = 1024;
static constexpr int F_ = 128;
static constexpr int S_ = 2;          // in-wave lane stagger (columns)
static constexpr int UDIM_ = 1296;    // skewed u-rows per stream (1149 used + slack)
static constexpr int LAG_ = 256;      // wave1 local-step lag = 4 superphases of 64
static constexpr int NSEGG_ = 22;     // superphases: (1152 + LAG_) / 64
static constexpr size_t STREAM_US = (size_t)B_ * 2 * UDIM_ * 512;  // ushorts

typedef __attribute__((ext_vector_type(8))) short short8;
typedef __attribute__((ext_vector_type(4))) float f32x4;

// RNE fp32x2 -> packed bf16x2 via the HW instruction
__device__ __forceinline__ unsigned pack2(float x, float y) {
  unsigned r;
  asm("v_cvt_pk_bf16_f32 %0, %1, %2" : "=v"(r) : "v"(x), "v"(y));
  return r;
}

// lane i <- lane i-1, whole-wave, as a VALU op (v_mov_b32_dpp wave_shr:1).
// Lane 0 keeps its own value - never consumed (l0-masked).
__device__ __forceinline__ float shfl_up1_dpp(float x) {
  int xi = __float_as_int(x);
  int r = __builtin_amdgcn_update_dpp(xi, xi, 0x138, 0xF, 0xF, false);  // wave_shr:1
  return __int_as_float(r);
}

// one wave per row of 128 floats; nrm[wid] = sum of squares
__global__ void norm_kernel(const float* __restrict__ s1, const float* __restrict__ s2,
                            float* __restrict__ nrm) {
  int gt   = blockIdx.x * blockDim.x + threadIdx.x;
  int wid  = gt >> 6;
  int lane = gt & 63;
  const float* src = (wid < B_ * L_) ? (s1 + (size_t)wid * F_)
                                     : (s2 + (size_t)(wid - B_ * L_) * F_);
  float2 v = ((const float2*)src)[lane];
  float s = v.x * v.x + v.y * v.y;
#pragma unroll
  for (int o = 32; o > 0; o >>= 1) s += __shfl_xor(s, o, 64);
  if (lane == 0) nrm[wid] = s;
}

// cost matrix -> bf16, two skewed streams per batch (one per dtw compute wave):
// global row r: w = r>>9, rl = r&511; element (r, col c) stored at
// stream[(b*2+w)][u = c + S_*(rl>>3)][rl]  (skew matches lane stagger S_).
// Measured round 2: staged-LDS coalesced write-out (256B dwordx4 runs).
__global__ __launch_bounds__(256) void cost_kernel(const float* __restrict__ s1,
                                                   const float* __restrict__ s2,
                                                   ushort* __restrict__ stream,
                                                   const float* __restrict__ nrm) {
  __shared__ __align__(16) ushort sbuf[2 * 128 * 136];  // aL+bL, reused as stage
  __shared__ float q1[128], q2[128];
  short (*aL)[136] = (short(*)[136])sbuf;
  short (*bL)[136] = (short(*)[136])(sbuf + 128 * 136);
  ushort (*stage)[136] = (ushort(*)[136])sbuf;  // rows 0..157 used; 272B row stride

  const int tid = threadIdx.x;
  const int b   = blockIdx.y;
  const int tc  = blockIdx.x & 7;
  const int tr  = blockIdx.x >> 3;

  const float* Ap = s1 + (size_t)b * L_ * F_ + (size_t)tr * 128 * F_;
  const float* Bp = s2 + (size_t)b * L_ * F_ + (size_t)tc * 128 * F_;

#pragma unroll 4
  for (int it = 0; it < 16; ++it) {
    int idx = it * 1024 + tid * 4;
    int r = idx >> 7, cc = idx & 127;
    float4 va = *(const float4*)(Ap + idx);
    float4 vb = *(const float4*)(Bp + idx);
    *(uint2*)&aL[r][cc] = make_uint2(pack2(va.x, va.y), pack2(va.z, va.w));
    *(uint2*)&bL[r][cc] = make_uint2(pack2(vb.x, vb.y), pack2(vb.z, vb.w));
  }
  if (tid < 128) q1[tid] = nrm[(size_t)b * L_ + tr * 128 + tid];
  else           q2[tid - 128] = nrm[(size_t)B_ * L_ + (size_t)b * L_ + tc * 128 + (tid - 128)];
  __syncthreads();

  const int wave = tid >> 6, lane = tid & 63, quad = lane >> 4, l16 = lane & 15;
  const int m0 = (wave >> 1) * 64, n0 = (wave & 1) * 64;

  f32x4 acc[4][4] = {};
#pragma unroll
  for (int kc = 0; kc < 4; ++kc) {
    short8 af[4], bf[4];
#pragma unroll
    for (int mi = 0; mi < 4; ++mi)
      af[mi] = *(const short8*)&aL[m0 + mi * 16 + l16][kc * 32 + quad * 8];
#pragma unroll
    for (int nj = 0; nj < 4; ++nj)
      bf[nj] = *(const short8*)&bL[n0 + nj * 16 + l16][kc * 32 + quad * 8];
#pragma unroll
    for (int mi = 0; mi < 4; ++mi)
#pragma unroll
      for (int nj = 0; nj < 4; ++nj)
        acc[mi][nj] = __builtin_amdgcn_mfma_f32_16x16x32_bf16(af[mi], bf[nj], acc[mi][nj], 0, 0, 0);
  }

  __syncthreads();  // all waves done reading aL/bL -> safe to reuse as stage

  // epilogue: sqrt-cost -> bf16, staged into LDS at local skewed-u layout
#pragma unroll
  for (int mi = 0; mi < 4; ++mi) {
    int lr = m0 + mi * 16 + quad * 4;   // 4-aligned; lr>>3 constant over the 4 rows
    int du = 2 * (lr >> 3);
    float a0 = q1[lr + 0], a1 = q1[lr + 1], a2 = q1[lr + 2], a3 = q1[lr + 3];
#pragma unroll
    for (int nj = 0; nj < 4; ++nj) {
      int lc = n0 + nj * 16 + l16;
      float qc = q2[lc];
      float vx = sqrtf(fmaxf(a0 + qc - 2.0f * acc[mi][nj][0], 0.0f));
      float vy = sqrtf(fmaxf(a1 + qc - 2.0f * acc[mi][nj][1], 0.0f));
      float vz = sqrtf(fmaxf(a2 + qc - 2.0f * acc[mi][nj][2], 0.0f));
      float vw = sqrtf(fmaxf(a3 + qc - 2.0f * acc[mi][nj][3], 0.0f));
      *(uint2*)&stage[lc + du][lr] = make_uint2(pack2(vx, vy), pack2(vz, vw));
    }
  }
  __syncthreads();

  // coalesced write-out: u-row u (0..157) -> global u-row ubase+u, rl run
  // rlbase..rlbase+127. 16 consecutive lanes cover one u-row's 256B.
  const int w      = tr >> 2;           // constant per block
  const int rlbase = (tr & 3) * 128;
  const int ubase  = tc * 128 + 32 * (tr & 3);
  ushort* Sb = stream + ((size_t)(b * 2 + w) * UDIM_ + ubase) * 512 + rlbase;
#pragma unroll
  for (int it = 0; it < 10; ++it) {
    int t = it * 256 + tid;
    if (t < 158 * 16) {
      int u = t >> 4, g = t & 15;
      if ((unsigned)(u - 2 * g) < 128u)  // chunk valid iff lc = u-2g in [0,128)
        *(uint4*)(Sb + (size_t)u * 512 + g * 8) = *(const uint4*)&stage[u][g * 8];
    }
  }
}

#define UNPACK_CV(cw, cv)                         \
  cv[0] = __uint_as_float((cw).x << 16);          \
  cv[1] = __uint_as_float((cw).x & 0xFFFF0000u);  \
  cv[2] = __uint_as_float((cw).y << 16);          \
  cv[3] = __uint_as_float((cw).y & 0xFFFF0000u);  \
  cv[4] = __uint_as_float((cw).z << 16);          \
  cv[5] = __uint_as_float((cw).z & 0xFFFF0000u);  \
  cv[6] = __uint_as_float((cw).w << 16);          \
  cv[7] = __uint_as_float((cw).w & 0xFFFF0000u);

#define CHAIN_BODY(head)                                            \
  {                                                                 \
    float cur = (head);                                             \
    float nl[8];                                                    \
    nl[0] = cur;                                                    \
    _Pragma("unroll") for (int r = 1; r < 8; ++r) {                 \
      cur = cv[r] + fminf(fminf(left[r - 1], left[r]), cur);        \
      nl[r] = cur;                                                  \
    }                                                               \
    _Pragma("unroll") for (int r = 0; r < 8; ++r) left[r] = nl[r];  \
    bot = nl[7];                                                    \
  }

// v7 = v6 per-wave code + SIMD-level TLP: one block = 512 threads = 8 waves =
// 4 independent batches (2 compute waves each), grid = 8. HW maps wave i ->
// SIMD i%4, so each SIMD hosts 2 waves from DIFFERENT batches whose
// independent instruction streams co-issue and fill each other's stalls
// (measured v6: ~50% of active-SIMD slots were stall). Per-wave bodies are
// verbatim v6 (hardware-validated); block barrier is a superset of each
// pair's barrier, hand-off margins unchanged (P=64, LAG=256, margin 62).
__global__ __launch_bounds__(512, 1) void dtw_kernel(const ushort* __restrict__ stream,
                                                     float* __restrict__ out) {
  __shared__ float hand[4][1040];  // per-batch row-511 D values; +16 slack

  const int tid  = threadIdx.x;
  const int wv   = (tid >> 6) & 1;       // 0 = rows 0..511, 1 = rows 512..1023
  const int bp   = tid >> 7;             // batch within block (0..3)
  const int b    = blockIdx.x * 4 + bp;
  const int lane = tid & 63;
  const bool l0 = (lane == 0);
  float* hp_ = hand[bp];

  // per-lane base: u-row u lives at src + u*512 (ushorts); lane slice 16B
  const ushort* src = stream + (size_t)(b * 2 + wv) * UDIM_ * 512 + lane * 8;

  float left[8];
#pragma unroll
  for (int r = 0; r < 8; ++r) left[r] = BIGV;
  float bot = BIGV;
  float sh[4] = {BIGV, BIGV, BIGV, BIGV};
  float hPrev = BIGV, result = 0.0f;
  float hRing[4];
  float hb[16];
  uint4 pre[16];

  // warm-up: local u-rows 0..15 (all stream data ready at launch)
#pragma unroll
  for (int i = 0; i < 16; ++i) pre[i] = *(const uint4*)(src + (size_t)i * 512);

  for (int n = 0; n < NSEGG_; ++n) {
    __syncthreads();  // hand[] writes >=1 superphase old visible to reader waves
    const int phaseS = 64 * n - (wv ? LAG_ : 0);

#pragma unroll 1
    for (int m = 0; m < 4; ++m) {
      const int sBase = phaseS + 16 * m;
      if ((unsigned)sBase >= 1152u) continue;  // chunk outside local range

      // fast: every lane active for all 16 steps of this chunk
      const bool fast = (sBase >= 128) & (sBase <= 1008);

      if (wv == 0) {
        if (fast) {
#pragma unroll
          for (int k = 0; k < 16; ++k) {
            float shN = shfl_up1_dpp(bot);
            uint4 cw = pre[k];
            // prefetch u-row 16 steps ahead (<= 1167 < UDIM_)
            pre[k] = *(const uint4*)(src + (size_t)(sBase + k + 16) * 512);
            float cv[8];
            UNPACK_CV(cw, cv)
            float dgT = l0 ? BIGV : sh[(k + 2) & 3];
            float upT = l0 ? BIGV : sh[(k + 3) & 3];
            CHAIN_BODY(cv[0] + fminf(fminf(dgT, upT), left[0]))
            sh[k & 3] = shN;
            hb[k] = bot;
          }
          if (lane == 63) {  // batched hand write: j = sBase-126 .. -111
            float4* hp = (float4*)&hp_[sBase - 126];
            hp[0] = make_float4(hb[0], hb[1], hb[2], hb[3]);
            hp[1] = make_float4(hb[4], hb[5], hb[6], hb[7]);
            hp[2] = make_float4(hb[8], hb[9], hb[10], hb[11]);
            hp[3] = make_float4(hb[12], hb[13], hb[14], hb[15]);
          }
        } else {
#pragma unroll
          for (int k = 0; k < 16; ++k) {
            const int s = sBase + k;
            const int col = s - S_ * lane;
            float shN = shfl_up1_dpp(bot);
            uint4 cw = pre[k];
            pre[k] = *(const uint4*)(src + (size_t)(sBase + k + 16) * 512);
            float cv[8];
            UNPACK_CV(cw, cv)
            float dgT = l0 ? ((s == 0) ? 0.0f : BIGV) : sh[(k + 2) & 3];
            float upT = l0 ? BIGV : sh[(k + 3) & 3];
            bool act = ((unsigned)col < 1024u);
            float c0 = act ? cv[0] : BIGV;  // head-only mask; induction keeps
                                            // inactive-lane state >= ~1e9
            CHAIN_BODY(c0 + fminf(fminf(dgT, upT), left[0]))
            sh[k & 3] = shN;
            int j = s - 126;  // lane63's column this step
            if (lane == 63 && (unsigned)j < 1024u) hp_[j] = bot;
          }
        }
      } else {
        if (fast) {
#pragma unroll
          for (int i = 0; i < 4; ++i) hRing[i] = hp_[sBase + i];
#pragma unroll
          for (int k = 0; k < 16; ++k) {
            float shN = shfl_up1_dpp(bot);
            float hCur = hRing[k & 3];
            uint4 cw = pre[k];
            pre[k] = *(const uint4*)(src + (size_t)(sBase + k + 16) * 512);
            hRing[k & 3] = hp_[sBase + k + 4];  // <= 1027 < 1040, in-bounds
            float cv[8];
            UNPACK_CV(cw, cv)
            float dgT = l0 ? hPrev : sh[(k + 2) & 3];
            float upT = l0 ? hCur : sh[(k + 3) & 3];
            CHAIN_BODY(cv[0] + fminf(fminf(dgT, upT), left[0]))
            sh[k & 3] = shN;
            hPrev = hCur;
          }
        } else {
#pragma unroll
          for (int i = 0; i < 4; ++i) hRing[i] = hp_[(sBase + i) & 1023];
#pragma unroll
          for (int k = 0; k < 16; ++k) {
            const int s = sBase + k;
            const int col = s - S_ * lane;
            float shN = shfl_up1_dpp(bot);
            float hCur = hRing[k & 3];
            uint4 cw = pre[k];
            pre[k] = *(const uint4*)(src + (size_t)(sBase + k + 16) * 512);
            hRing[k & 3] = hp_[(s + 4) & 1023];
            float cv[8];
            UNPACK_CV(cw, cv)
            float dgT = l0 ? ((s == 0) ? BIGV : hPrev) : sh[(k + 2) & 3];
            float upT = l0 ? hCur : sh[(k + 3) & 3];
            bool act = ((unsigned)col < 1024u);
            float c0 = act ? cv[0] : BIGV;
            CHAIN_BODY(c0 + fminf(fminf(dgT, upT), left[0]))
            sh[k & 3] = shN;
            hPrev = hCur;
            if (s == 1149) result = bot;  // lane63 at col 1023: D[1024][1024]
          }
        }
      }
    }
  }
  if (wv == 1 && lane == 63) out[b] = 1.0f / (1.0f + result * (1.0f / 2048.0f));
}

extern "C" void kernel_launch(void* const* d_in, const int* in_sizes, int n_in,
                              void* d_out, int out_size, void* d_ws, size_t ws_size,
                              hipStream_t stream_) {
  const float* s1 = (const float*)d_in[0];
  const float* s2 = (const float*)d_in[1];
  float* out = (float*)d_out;
  ushort* cws = (ushort*)d_ws;
  float* nrm = (float*)(cws + STREAM_US);

  norm_kernel<<<dim3((2 * B_ * L_) / 4), 256, 0, stream_>>>(s1, s2, nrm);
  cost_kernel<<<dim3(64, B_), 256, 0, stream_>>>(s1, s2, cws, nrm);
  dtw_kernel<<<dim3(B_ / 4), 512, 0, stream_>>>(cws, out);
}

// Round 11
// 236.753 us; speedup vs baseline: 1.2181x; 1.2181x over previous
//
#include <hip/hip_runtime.h>
#include <hip/hip_bf16.h>

#define BIGV 1.0e9f

static constexpr int B_ = 32;
static constexpr int L_ = 1024;
static constexpr int F_ = 128;
static constexpr int S_ = 2;          // in-wave lane stagger (columns)
static constexpr int UDIM_ = 1296;    // skewed u-rows per stream (1149 used + slack)
static constexpr int LAG_ = 256;      // wave1 local-step lag = 4 superphases of 64
static constexpr int NSEGG_ = 22;     // superphases: (1152 + LAG_) / 64
static constexpr size_t STREAM_US = (size_t)B_ * 2 * UDIM_ * 512;  // ushorts

typedef __attribute__((ext_vector_type(8))) short short8;
typedef __attribute__((ext_vector_type(4))) float f32x4;

// RNE fp32x2 -> packed bf16x2 via the HW instruction
__device__ __forceinline__ unsigned pack2(float x, float y) {
  unsigned r;
  asm("v_cvt_pk_bf16_f32 %0, %1, %2" : "=v"(r) : "v"(x), "v"(y));
  return r;
}

// lane i <- lane i-1, whole-wave, as a VALU op (v_mov_b32_dpp wave_shr:1).
// Lane 0 keeps its own value - never consumed (l0-masked).
__device__ __forceinline__ float shfl_up1_dpp(float x) {
  int xi = __float_as_int(x);
  int r = __builtin_amdgcn_update_dpp(xi, xi, 0x138, 0xF, 0xF, false);  // wave_shr:1
  return __int_as_float(r);
}

// 3-input min in one VOP3 (replaces fminf(fminf(a,b),c): -1 inst, same 8cy
// dep path through c).
__device__ __forceinline__ float min3f(float a, float b, float c) {
  float r;
  asm("v_min3_f32 %0, %1, %2, %3" : "=v"(r) : "v"(a), "v"(b), "v"(c));
  return r;
}

// one wave per row of 128 floats; nrm[wid] = sum of squares
__global__ void norm_kernel(const float* __restrict__ s1, const float* __restrict__ s2,
                            float* __restrict__ nrm) {
  int gt   = blockIdx.x * blockDim.x + threadIdx.x;
  int wid  = gt >> 6;
  int lane = gt & 63;
  const float* src = (wid < B_ * L_) ? (s1 + (size_t)wid * F_)
                                     : (s2 + (size_t)(wid - B_ * L_) * F_);
  float2 v = ((const float2*)src)[lane];
  float s = v.x * v.x + v.y * v.y;
#pragma unroll
  for (int o = 32; o > 0; o >>= 1) s += __shfl_xor(s, o, 64);
  if (lane == 0) nrm[wid] = s;
}

// cost matrix -> bf16, two skewed streams per batch (one per dtw compute wave):
// global row r: w = r>>9, rl = r&511; element (r, col c) stored at
// stream[(b*2+w)][u = c + S_*(rl>>3)][rl]  (skew matches lane stagger S_).
// Measured round 2: staged-LDS coalesced write-out (256B dwordx4 runs).
__global__ __launch_bounds__(256) void cost_kernel(const float* __restrict__ s1,
                                                   const float* __restrict__ s2,
                                                   ushort* __restrict__ stream,
                                                   const float* __restrict__ nrm) {
  __shared__ __align__(16) ushort sbuf[2 * 128 * 136];  // aL+bL, reused as stage
  __shared__ float q1[128], q2[128];
  short (*aL)[136] = (short(*)[136])sbuf;
  short (*bL)[136] = (short(*)[136])(sbuf + 128 * 136);
  ushort (*stage)[136] = (ushort(*)[136])sbuf;  // rows 0..157 used; 272B row stride

  const int tid = threadIdx.x;
  const int b   = blockIdx.y;
  const int tc  = blockIdx.x & 7;
  const int tr  = blockIdx.x >> 3;

  const float* Ap = s1 + (size_t)b * L_ * F_ + (size_t)tr * 128 * F_;
  const float* Bp = s2 + (size_t)b * L_ * F_ + (size_t)tc * 128 * F_;

#pragma unroll 4
  for (int it = 0; it < 16; ++it) {
    int idx = it * 1024 + tid * 4;
    int r = idx >> 7, cc = idx & 127;
    float4 va = *(const float4*)(Ap + idx);
    float4 vb = *(const float4*)(Bp + idx);
    *(uint2*)&aL[r][cc] = make_uint2(pack2(va.x, va.y), pack2(va.z, va.w));
    *(uint2*)&bL[r][cc] = make_uint2(pack2(vb.x, vb.y), pack2(vb.z, vb.w));
  }
  if (tid < 128) q1[tid] = nrm[(size_t)b * L_ + tr * 128 + tid];
  else           q2[tid - 128] = nrm[(size_t)B_ * L_ + (size_t)b * L_ + tc * 128 + (tid - 128)];
  __syncthreads();

  const int wave = tid >> 6, lane = tid & 63, quad = lane >> 4, l16 = lane & 15;
  const int m0 = (wave >> 1) * 64, n0 = (wave & 1) * 64;

  f32x4 acc[4][4] = {};
#pragma unroll
  for (int kc = 0; kc < 4; ++kc) {
    short8 af[4], bf[4];
#pragma unroll
    for (int mi = 0; mi < 4; ++mi)
      af[mi] = *(const short8*)&aL[m0 + mi * 16 + l16][kc * 32 + quad * 8];
#pragma unroll
    for (int nj = 0; nj < 4; ++nj)
      bf[nj] = *(const short8*)&bL[n0 + nj * 16 + l16][kc * 32 + quad * 8];
#pragma unroll
    for (int mi = 0; mi < 4; ++mi)
#pragma unroll
      for (int nj = 0; nj < 4; ++nj)
        acc[mi][nj] = __builtin_amdgcn_mfma_f32_16x16x32_bf16(af[mi], bf[nj], acc[mi][nj], 0, 0, 0);
  }

  __syncthreads();  // all waves done reading aL/bL -> safe to reuse as stage

  // epilogue: sqrt-cost -> bf16, staged into LDS at local skewed-u layout
#pragma unroll
  for (int mi = 0; mi < 4; ++mi) {
    int lr = m0 + mi * 16 + quad * 4;   // 4-aligned; lr>>3 constant over the 4 rows
    int du = 2 * (lr >> 3);
    float a0 = q1[lr + 0], a1 = q1[lr + 1], a2 = q1[lr + 2], a3 = q1[lr + 3];
#pragma unroll
    for (int nj = 0; nj < 4; ++nj) {
      int lc = n0 + nj * 16 + l16;
      float qc = q2[lc];
      float vx = sqrtf(fmaxf(a0 + qc - 2.0f * acc[mi][nj][0], 0.0f));
      float vy = sqrtf(fmaxf(a1 + qc - 2.0f * acc[mi][nj][1], 0.0f));
      float vz = sqrtf(fmaxf(a2 + qc - 2.0f * acc[mi][nj][2], 0.0f));
      float vw = sqrtf(fmaxf(a3 + qc - 2.0f * acc[mi][nj][3], 0.0f));
      *(uint2*)&stage[lc + du][lr] = make_uint2(pack2(vx, vy), pack2(vz, vw));
    }
  }
  __syncthreads();

  // coalesced write-out: u-row u (0..157) -> global u-row ubase+u, rl run
  // rlbase..rlbase+127. 16 consecutive lanes cover one u-row's 256B.
  const int w      = tr >> 2;           // constant per block
  const int rlbase = (tr & 3) * 128;
  const int ubase  = tc * 128 + 32 * (tr & 3);
  ushort* Sb = stream + ((size_t)(b * 2 + w) * UDIM_ + ubase) * 512 + rlbase;
#pragma unroll
  for (int it = 0; it < 10; ++it) {
    int t = it * 256 + tid;
    if (t < 158 * 16) {
      int u = t >> 4, g = t & 15;
      if ((unsigned)(u - 2 * g) < 128u)  // chunk valid iff lc = u-2g in [0,128)
        *(uint4*)(Sb + (size_t)u * 512 + g * 8) = *(const uint4*)&stage[u][g * 8];
    }
  }
}

#define UNPACK_CV(cw, cv)                         \
  cv[0] = __uint_as_float((cw).x << 16);          \
  cv[1] = __uint_as_float((cw).x & 0xFFFF0000u);  \
  cv[2] = __uint_as_float((cw).y << 16);          \
  cv[3] = __uint_as_float((cw).y & 0xFFFF0000u);  \
  cv[4] = __uint_as_float((cw).z << 16);          \
  cv[5] = __uint_as_float((cw).z & 0xFFFF0000u);  \
  cv[6] = __uint_as_float((cw).w << 16);          \
  cv[7] = __uint_as_float((cw).w & 0xFFFF0000u);

#define CHAIN_BODY(head)                                            \
  {                                                                 \
    float cur = (head);                                             \
    float nl[8];                                                    \
    nl[0] = cur;                                                    \
    _Pragma("unroll") for (int r = 1; r < 8; ++r) {                 \
      cur = cv[r] + min3f(left[r - 1], left[r], cur);               \
      nl[r] = cur;                                                  \
    }                                                               \
    _Pragma("unroll") for (int r = 0; r < 8; ++r) left[r] = nl[r];  \
    bot = nl[7];                                                    \
  }

// v8 = v6 structure (measured best: 115us, 32 CUs, 1 wave/SIMD) + instruction
// diet: v_min3_f32 chain (-8 inst/step) and wave0 pre-masked sh stores
// (-1 inst/step). v7 proved co-issue helps per-SIMD (1.32x) but costs CUs;
// with fixed 64-wave work the only lever left is issue-slot count per step.
//   wave0: DTW rows 0..511 (8 rows/lane); stores sh pre-masked (lane0 -> BIGV,
//          exactly the old masked-read semantics); writes hand[] per 16-chunk
//   wave1: rows 512..1023, lag LAG_=256; lane0 substitutes hPrev/hCur (cndmask
//          kept); reads hand[] via 4-deep register ring
// Hand-off algebra @P=64: writer publishes j <= 64n-127 by barrier n; reader
// reads j <= 64n-256+67 = 64n-189 -> margin 62. Fast window [128,1008] and
// tail masking verbatim v3/v6 (hardware-validated).
__global__ __launch_bounds__(128, 1) void dtw_kernel(const ushort* __restrict__ stream,
                                                     float* __restrict__ out) {
  __shared__ float hand[1040];  // row-511 D values; +16 slack for unmasked prefetch

  const int b    = blockIdx.x;
  const int tid  = threadIdx.x;
  const int wave = tid >> 6;
  const int lane = tid & 63;
  const bool l0 = (lane == 0);

  // per-lane base: u-row u lives at src + u*512 (ushorts); lane slice 16B
  const ushort* src = stream + (size_t)(b * 2 + wave) * UDIM_ * 512 + lane * 8;

  float left[8];
#pragma unroll
  for (int r = 0; r < 8; ++r) left[r] = BIGV;
  float bot = BIGV;
  float sh[4] = {BIGV, BIGV, BIGV, BIGV};
  float hPrev = BIGV, result = 0.0f;
  float hRing[4];
  float hb[16];
  uint4 pre[16];

  // warm-up: local u-rows 0..15 (all stream data ready at launch)
#pragma unroll
  for (int i = 0; i < 16; ++i) pre[i] = *(const uint4*)(src + (size_t)i * 512);

  for (int n = 0; n < NSEGG_; ++n) {
    __syncthreads();  // hand[] writes >=1 superphase old visible to wave1
    const int phaseS = 64 * n - (wave ? LAG_ : 0);

#pragma unroll 1
    for (int m = 0; m < 4; ++m) {
      const int sBase = phaseS + 16 * m;
      if ((unsigned)sBase >= 1152u) continue;  // chunk outside local range

      // fast: every lane active for all 16 steps of this chunk
      const bool fast = (sBase >= 128) & (sBase <= 1008);

      if (wave == 0) {
        if (fast) {
#pragma unroll
          for (int k = 0; k < 16; ++k) {
            float shN = shfl_up1_dpp(bot);
            uint4 cw = pre[k];
            // prefetch u-row 16 steps ahead (<= 1167 < UDIM_)
            pre[k] = *(const uint4*)(src + (size_t)(sBase + k + 16) * 512);
            float cv[8];
            UNPACK_CV(cw, cv)
            // sh pre-masked: lane0 slots always BIGV
            float dgT = sh[(k + 2) & 3];
            float upT = sh[(k + 3) & 3];
            CHAIN_BODY(cv[0] + min3f(dgT, upT, left[0]))
            sh[k & 3] = l0 ? BIGV : shN;
            hb[k] = bot;
          }
          if (lane == 63) {  // batched hand write: j = sBase-126 .. -111
            float4* hp = (float4*)&hand[sBase - 126];
            hp[0] = make_float4(hb[0], hb[1], hb[2], hb[3]);
            hp[1] = make_float4(hb[4], hb[5], hb[6], hb[7]);
            hp[2] = make_float4(hb[8], hb[9], hb[10], hb[11]);
            hp[3] = make_float4(hb[12], hb[13], hb[14], hb[15]);
          }
        } else {
#pragma unroll
          for (int k = 0; k < 16; ++k) {
            const int s = sBase + k;
            const int col = s - S_ * lane;
            float shN = shfl_up1_dpp(bot);
            uint4 cw = pre[k];
            pre[k] = *(const uint4*)(src + (size_t)(sBase + k + 16) * 512);
            float cv[8];
            UNPACK_CV(cw, cv)
            // sh pre-masked (lane0 -> BIGV); only the s==0 D[0][0] seed differs
            float dgT = sh[(k + 2) & 3];
            if (l0 && s == 0) dgT = 0.0f;
            float upT = sh[(k + 3) & 3];
            bool act = ((unsigned)col < 1024u);
            float c0 = act ? cv[0] : BIGV;  // head-only mask; induction keeps
                                            // inactive-lane state >= ~1e9
            CHAIN_BODY(c0 + min3f(dgT, upT, left[0]))
            sh[k & 3] = l0 ? BIGV : shN;
            int j = s - 126;  // lane63's column this step
            if (lane == 63 && (unsigned)j < 1024u) hand[j] = bot;
          }
        }
      } else {
        if (fast) {
#pragma unroll
          for (int i = 0; i < 4; ++i) hRing[i] = hand[sBase + i];
#pragma unroll
          for (int k = 0; k < 16; ++k) {
            float shN = shfl_up1_dpp(bot);
            float hCur = hRing[k & 3];
            uint4 cw = pre[k];
            pre[k] = *(const uint4*)(src + (size_t)(sBase + k + 16) * 512);
            hRing[k & 3] = hand[sBase + k + 4];  // <= 1027 < 1040, in-bounds
            float cv[8];
            UNPACK_CV(cw, cv)
            float dgT = l0 ? hPrev : sh[(k + 2) & 3];
            float upT = l0 ? hCur : sh[(k + 3) & 3];
            CHAIN_BODY(cv[0] + min3f(dgT, upT, left[0]))
            sh[k & 3] = shN;
            hPrev = hCur;
          }
        } else {
#pragma unroll
          for (int i = 0; i < 4; ++i) hRing[i] = hand[(sBase + i) & 1023];
#pragma unroll
          for (int k = 0; k < 16; ++k) {
            const int s = sBase + k;
            const int col = s - S_ * lane;
            float shN = shfl_up1_dpp(bot);
            float hCur = hRing[k & 3];
            uint4 cw = pre[k];
            pre[k] = *(const uint4*)(src + (size_t)(sBase + k + 16) * 512);
            hRing[k & 3] = hand[(s + 4) & 1023];
            float cv[8];
            UNPACK_CV(cw, cv)
            float dgT = l0 ? ((s == 0) ? BIGV : hPrev) : sh[(k + 2) & 3];
            float upT = l0 ? hCur : sh[(k + 3) & 3];
            bool act = ((unsigned)col < 1024u);
            float c0 = act ? cv[0] : BIGV;
            CHAIN_BODY(c0 + min3f(dgT, upT, left[0]))
            sh[k & 3] = shN;
            hPrev = hCur;
            if (s == 1149) result = bot;  // lane63 at col 1023: D[1024][1024]
          }
        }
      }
    }
  }
  if (wave == 1 && lane == 63) out[b] = 1.0f / (1.0f + result * (1.0f / 2048.0f));
}

extern "C" void kernel_launch(void* const* d_in, const int* in_sizes, int n_in,
                              void* d_out, int out_size, void* d_ws, size_t ws_size,
                              hipStream_t stream_) {
  const float* s1 = (const float*)d_in[0];
  const float* s2 = (const float*)d_in[1];
  float* out = (float*)d_out;
  ushort* cws = (ushort*)d_ws;
  float* nrm = (float*)(cws + STREAM_US);

  norm_kernel<<<dim3((2 * B_ * L_) / 4), 256, 0, stream_>>>(s1, s2, nrm);
  cost_kernel<<<dim3(64, B_), 256, 0, stream_>>>(s1, s2, cws, nrm);
  dtw_kernel<<<dim3(B_), 128, 0, stream_>>>(cws, out);
}

// Round 12
// 229.485 us; speedup vs baseline: 1.2567x; 1.0317x over previous
//
#include <hip/hip_runtime.h>
#include <hip/hip_bf16.h>

#define BIGV 1.0e9f

static constexpr int B_ = 32;
static constexpr int L_ = 1024;
static constexpr int F_ = 128;
static constexpr int S_ = 2;          // in-wave lane stagger (columns)
static constexpr int UDIM_ = 1296;    // skewed u-rows per stream (1149 used + slack)
static constexpr int LAG_ = 192;      // wave1 local-step lag = 6 phases of 32 (margin 34)
static constexpr int NSEGG_ = 42;     // phases: (1152 + LAG_) / 32
static constexpr size_t STREAM_US = (size_t)B_ * 2 * UDIM_ * 512;  // ushorts

typedef __attribute__((ext_vector_type(8))) short short8;
typedef __attribute__((ext_vector_type(4))) float f32x4;

// RNE fp32x2 -> packed bf16x2 via the HW instruction
__device__ __forceinline__ unsigned pack2(float x, float y) {
  unsigned r;
  asm("v_cvt_pk_bf16_f32 %0, %1, %2" : "=v"(r) : "v"(x), "v"(y));
  return r;
}

// lane i <- lane i-1, whole-wave, as a VALU op (v_mov_b32_dpp wave_shr:1).
// Lane 0 keeps its own value - never consumed (l0-masked).
__device__ __forceinline__ float shfl_up1_dpp(float x) {
  int xi = __float_as_int(x);
  int r = __builtin_amdgcn_update_dpp(xi, xi, 0x138, 0xF, 0xF, false);  // wave_shr:1
  return __int_as_float(r);
}

// 3-input min in one VOP3
__device__ __forceinline__ float min3f(float a, float b, float c) {
  float r;
  asm("v_min3_f32 %0, %1, %2, %3" : "=v"(r) : "v"(a), "v"(b), "v"(c));
  return r;
}

// one wave per row of 128 floats; nrm[wid] = sum of squares
__global__ void norm_kernel(const float* __restrict__ s1, const float* __restrict__ s2,
                            float* __restrict__ nrm) {
  int gt   = blockIdx.x * blockDim.x + threadIdx.x;
  int wid  = gt >> 6;
  int lane = gt & 63;
  const float* src = (wid < B_ * L_) ? (s1 + (size_t)wid * F_)
                                     : (s2 + (size_t)(wid - B_ * L_) * F_);
  float2 v = ((const float2*)src)[lane];
  float s = v.x * v.x + v.y * v.y;
#pragma unroll
  for (int o = 32; o > 0; o >>= 1) s += __shfl_xor(s, o, 64);
  if (lane == 0) nrm[wid] = s;
}

// cost matrix -> bf16, two skewed streams per batch (one per dtw compute wave):
// global row r: w = r>>9, rl = r&511; element (r, col c) stored at
// stream[(b*2+w)][u = c + S_*(rl>>3)][rl]  (skew matches lane stagger S_).
// Measured round 2: staged-LDS coalesced write-out (256B dwordx4 runs).
__global__ __launch_bounds__(256) void cost_kernel(const float* __restrict__ s1,
                                                   const float* __restrict__ s2,
                                                   ushort* __restrict__ stream,
                                                   const float* __restrict__ nrm) {
  __shared__ __align__(16) ushort sbuf[2 * 128 * 136];  // aL+bL, reused as stage
  __shared__ float q1[128], q2[128];
  short (*aL)[136] = (short(*)[136])sbuf;
  short (*bL)[136] = (short(*)[136])(sbuf + 128 * 136);
  ushort (*stage)[136] = (ushort(*)[136])sbuf;  // rows 0..157 used; 272B row stride

  const int tid = threadIdx.x;
  const int b   = blockIdx.y;
  const int tc  = blockIdx.x & 7;
  const int tr  = blockIdx.x >> 3;

  const float* Ap = s1 + (size_t)b * L_ * F_ + (size_t)tr * 128 * F_;
  const float* Bp = s2 + (size_t)b * L_ * F_ + (size_t)tc * 128 * F_;

#pragma unroll 4
  for (int it = 0; it < 16; ++it) {
    int idx = it * 1024 + tid * 4;
    int r = idx >> 7, cc = idx & 127;
    float4 va = *(const float4*)(Ap + idx);
    float4 vb = *(const float4*)(Bp + idx);
    *(uint2*)&aL[r][cc] = make_uint2(pack2(va.x, va.y), pack2(va.z, va.w));
    *(uint2*)&bL[r][cc] = make_uint2(pack2(vb.x, vb.y), pack2(vb.z, vb.w));
  }
  if (tid < 128) q1[tid] = nrm[(size_t)b * L_ + tr * 128 + tid];
  else           q2[tid - 128] = nrm[(size_t)B_ * L_ + (size_t)b * L_ + tc * 128 + (tid - 128)];
  __syncthreads();

  const int wave = tid >> 6, lane = tid & 63, quad = lane >> 4, l16 = lane & 15;
  const int m0 = (wave >> 1) * 64, n0 = (wave & 1) * 64;

  f32x4 acc[4][4] = {};
#pragma unroll
  for (int kc = 0; kc < 4; ++kc) {
    short8 af[4], bf[4];
#pragma unroll
    for (int mi = 0; mi < 4; ++mi)
      af[mi] = *(const short8*)&aL[m0 + mi * 16 + l16][kc * 32 + quad * 8];
#pragma unroll
    for (int nj = 0; nj < 4; ++nj)
      bf[nj] = *(const short8*)&bL[n0 + nj * 16 + l16][kc * 32 + quad * 8];
#pragma unroll
    for (int mi = 0; mi < 4; ++mi)
#pragma unroll
      for (int nj = 0; nj < 4; ++nj)
        acc[mi][nj] = __builtin_amdgcn_mfma_f32_16x16x32_bf16(af[mi], bf[nj], acc[mi][nj], 0, 0, 0);
  }

  __syncthreads();  // all waves done reading aL/bL -> safe to reuse as stage

  // epilogue: sqrt-cost -> bf16, staged into LDS at local skewed-u layout
#pragma unroll
  for (int mi = 0; mi < 4; ++mi) {
    int lr = m0 + mi * 16 + quad * 4;   // 4-aligned; lr>>3 constant over the 4 rows
    int du = 2 * (lr >> 3);
    float a0 = q1[lr + 0], a1 = q1[lr + 1], a2 = q1[lr + 2], a3 = q1[lr + 3];
#pragma unroll
    for (int nj = 0; nj < 4; ++nj) {
      int lc = n0 + nj * 16 + l16;
      float qc = q2[lc];
      float vx = sqrtf(fmaxf(a0 + qc - 2.0f * acc[mi][nj][0], 0.0f));
      float vy = sqrtf(fmaxf(a1 + qc - 2.0f * acc[mi][nj][1], 0.0f));
      float vz = sqrtf(fmaxf(a2 + qc - 2.0f * acc[mi][nj][2], 0.0f));
      float vw = sqrtf(fmaxf(a3 + qc - 2.0f * acc[mi][nj][3], 0.0f));
      *(uint2*)&stage[lc + du][lr] = make_uint2(pack2(vx, vy), pack2(vz, vw));
    }
  }
  __syncthreads();

  // coalesced write-out: u-row u (0..157) -> global u-row ubase+u, rl run
  // rlbase..rlbase+127. 16 consecutive lanes cover one u-row's 256B.
  const int w      = tr >> 2;           // constant per block
  const int rlbase = (tr & 3) * 128;
  const int ubase  = tc * 128 + 32 * (tr & 3);
  ushort* Sb = stream + ((size_t)(b * 2 + w) * UDIM_ + ubase) * 512 + rlbase;
#pragma unroll
  for (int it = 0; it < 10; ++it) {
    int t = it * 256 + tid;
    if (t < 158 * 16) {
      int u = t >> 4, g = t & 15;
      if ((unsigned)(u - 2 * g) < 128u)  // chunk valid iff lc = u-2g in [0,128)
        *(uint4*)(Sb + (size_t)u * 512 + g * 8) = *(const uint4*)&stage[u][g * 8];
    }
  }
}

#define UNPACK_CV(cw, cv)                         \
  cv[0] = __uint_as_float((cw).x << 16);          \
  cv[1] = __uint_as_float((cw).x & 0xFFFF0000u);  \
  cv[2] = __uint_as_float((cw).y << 16);          \
  cv[3] = __uint_as_float((cw).y & 0xFFFF0000u);  \
  cv[4] = __uint_as_float((cw).z << 16);          \
  cv[5] = __uint_as_float((cw).z & 0xFFFF0000u);  \
  cv[6] = __uint_as_float((cw).w << 16);          \
  cv[7] = __uint_as_float((cw).w & 0xFFFF0000u);

#define CHAIN_BODY(head)                                            \
  {                                                                 \
    float cur = (head);                                             \
    float nl[8];                                                    \
    nl[0] = cur;                                                    \
    _Pragma("unroll") for (int r = 1; r < 8; ++r) {                 \
      cur = cv[r] + min3f(left[r - 1], left[r], cur);               \
      nl[r] = cur;                                                  \
    }                                                               \
    _Pragma("unroll") for (int r = 0; r < 8; ++r) left[r] = nl[r];  \
    bot = nl[7];                                                    \
  }

// v9: phase = ONE straight-line 32-step body per barrier (no inner chunk
// loop). Across v3-v8 the per-16-step-chunk cost was invariant (~3100cy)
// regardless of content -> the cost sits at the chunk-loop back-edge
// (conservative compiler vmcnt drain on the loop-carried pre[] ring) plus
// the barrier drain. Removing the inner loop leaves exactly one drain per
// 32 steps (at the barrier, unavoidable) vs 5 per 64 steps before.
// Ring depth 32 (pre[32]); LAG=192 (margin 34: consumed hand <= 32n-161,
// published <= 32n-127; k>=28 hRing prefetches are dead - overwritten by
// next phase's preload before use). Fast window [128,992] for 32 steps.
// Per-step semantics verbatim v8 (hardware-validated).
__global__ __launch_bounds__(128, 1) void dtw_kernel(const ushort* __restrict__ stream,
                                                     float* __restrict__ out) {
  __shared__ float hand[1040];  // row-511 D values; +16 slack for unmasked prefetch

  const int b    = blockIdx.x;
  const int tid  = threadIdx.x;
  const int wave = tid >> 6;
  const int lane = tid & 63;
  const bool l0 = (lane == 0);

  // per-lane base: u-row u lives at src + u*512 (ushorts); lane slice 16B
  const ushort* src = stream + (size_t)(b * 2 + wave) * UDIM_ * 512 + lane * 8;

  float left[8];
#pragma unroll
  for (int r = 0; r < 8; ++r) left[r] = BIGV;
  float bot = BIGV;
  float sh[4] = {BIGV, BIGV, BIGV, BIGV};
  float hPrev = BIGV, result = 0.0f;
  float hRing[4];
  float hb[32];
  uint4 pre[32];

  // warm-up: local u-rows 0..31 (all stream data ready at launch)
#pragma unroll
  for (int i = 0; i < 32; ++i) pre[i] = *(const uint4*)(src + (size_t)i * 512);

  for (int n = 0; n < NSEGG_; ++n) {
    __syncthreads();  // hand[] writes >=1 phase old visible to wave1
    const int sBase = 32 * n - (wave ? LAG_ : 0);
    if ((unsigned)sBase >= 1152u) continue;  // idle phase (barrier already hit)

    // fast: every lane active for all 32 steps (lane63 started: sBase>=126;
    // lane0 not finished: sBase+31 <= 1023)
    const bool fast = (sBase >= 128) & (sBase <= 992);

    if (wave == 0) {
      if (fast) {
#pragma unroll
        for (int k = 0; k < 32; ++k) {
          float shN = shfl_up1_dpp(bot);
          uint4 cw = pre[k];
          // prefetch u-row 32 steps ahead (<= 1183 < UDIM_)
          pre[k] = *(const uint4*)(src + (size_t)(sBase + k + 32) * 512);
          float cv[8];
          UNPACK_CV(cw, cv)
          // sh pre-masked: lane0 slots always BIGV
          float dgT = sh[(k + 2) & 3];
          float upT = sh[(k + 3) & 3];
          CHAIN_BODY(cv[0] + min3f(dgT, upT, left[0]))
          sh[k & 3] = l0 ? BIGV : shN;
          hb[k] = bot;
        }
        if (lane == 63) {  // batched hand write: j = sBase-126 .. sBase-95
          float4* hp = (float4*)&hand[sBase - 126];
#pragma unroll
          for (int q = 0; q < 8; ++q)
            hp[q] = make_float4(hb[4 * q], hb[4 * q + 1], hb[4 * q + 2], hb[4 * q + 3]);
        }
      } else {
#pragma unroll
        for (int k = 0; k < 32; ++k) {
          const int s = sBase + k;
          const int col = s - S_ * lane;
          float shN = shfl_up1_dpp(bot);
          uint4 cw = pre[k];
          pre[k] = *(const uint4*)(src + (size_t)(sBase + k + 32) * 512);
          float cv[8];
          UNPACK_CV(cw, cv)
          // sh pre-masked (lane0 -> BIGV); only the s==0 D[0][0] seed differs
          float dgT = sh[(k + 2) & 3];
          if (l0 && s == 0) dgT = 0.0f;
          float upT = sh[(k + 3) & 3];
          bool act = ((unsigned)col < 1024u);
          float c0 = act ? cv[0] : BIGV;  // head-only mask; induction keeps
                                          // inactive-lane state >= ~1e9
          CHAIN_BODY(c0 + min3f(dgT, upT, left[0]))
          sh[k & 3] = l0 ? BIGV : shN;
          int j = s - 126;  // lane63's column this step
          if (lane == 63 && (unsigned)j < 1024u) hand[j] = bot;
        }
      }
    } else {
      if (fast) {
#pragma unroll
        for (int i = 0; i < 4; ++i) hRing[i] = hand[sBase + i];
#pragma unroll
        for (int k = 0; k < 32; ++k) {
          float shN = shfl_up1_dpp(bot);
          float hCur = hRing[k & 3];
          uint4 cw = pre[k];
          pre[k] = *(const uint4*)(src + (size_t)(sBase + k + 32) * 512);
          hRing[k & 3] = hand[sBase + k + 4];  // <= 1027 < 1040; k>=28 slots
                                               // dead (re-preloaded next phase)
          float cv[8];
          UNPACK_CV(cw, cv)
          float dgT = l0 ? hPrev : sh[(k + 2) & 3];
          float upT = l0 ? hCur : sh[(k + 3) & 3];
          CHAIN_BODY(cv[0] + min3f(dgT, upT, left[0]))
          sh[k & 3] = shN;
          hPrev = hCur;
        }
      } else {
#pragma unroll
        for (int i = 0; i < 4; ++i) hRing[i] = hand[(sBase + i) & 1023];
#pragma unroll
        for (int k = 0; k < 32; ++k) {
          const int s = sBase + k;
          const int col = s - S_ * lane;
          float shN = shfl_up1_dpp(bot);
          float hCur = hRing[k & 3];
          uint4 cw = pre[k];
          pre[k] = *(const uint4*)(src + (size_t)(sBase + k + 32) * 512);
          hRing[k & 3] = hand[(s + 4) & 1023];
          float cv[8];
          UNPACK_CV(cw, cv)
          float dgT = l0 ? ((s == 0) ? BIGV : hPrev) : sh[(k + 2) & 3];
          float upT = l0 ? hCur : sh[(k + 3) & 3];
          bool act = ((unsigned)col < 1024u);
          float c0 = act ? cv[0] : BIGV;
          CHAIN_BODY(c0 + min3f(dgT, upT, left[0]))
          sh[k & 3] = shN;
          hPrev = hCur;
          if (s == 1149) result = bot;  // lane63 at col 1023: D[1024][1024]
        }
      }
    }
  }
  if (wave == 1 && lane == 63) out[b] = 1.0f / (1.0f + result * (1.0f / 2048.0f));
}

extern "C" void kernel_launch(void* const* d_in, const int* in_sizes, int n_in,
                              void* d_out, int out_size, void* d_ws, size_t ws_size,
                              hipStream_t stream_) {
  const float* s1 = (const float*)d_in[0];
  const float* s2 = (const float*)d_in[1];
  float* out = (float*)d_out;
  ushort* cws = (ushort*)d_ws;
  float* nrm = (float*)(cws + STREAM_US);

  norm_kernel<<<dim3((2 * B_ * L_) / 4), 256, 0, stream_>>>(s1, s2, nrm);
  cost_kernel<<<dim3(64, B_), 256, 0, stream_>>>(s1, s2, cws, nrm);
  dtw_kernel<<<dim3(B_), 128, 0, stream_>>>(cws, out);
}

// Round 13
// 223.373 us; speedup vs baseline: 1.2911x; 1.0274x over previous
//
#include <hip/hip_runtime.h>
#include <hip/hip_bf16.h>

#define BIGV 1.0e9f

static constexpr int B_ = 32;
static constexpr int L_ = 1024;
static constexpr int F_ = 128;
static constexpr int UD2_ = 592;      // skewed u-rows per stream (574 used + prefetch slack)
static constexpr int LAGP_ = 96;      // wave1 lag in pair-steps (6 phases of 16; margin 26 cols)
static constexpr int NSEGP_ = 42;     // phases: 36 + 6
static constexpr size_t STREAM_US = (size_t)B_ * 2 * UD2_ * 1024;  // ushorts (77.6 MB)

typedef __attribute__((ext_vector_type(8))) short short8;
typedef __attribute__((ext_vector_type(4))) float f32x4;

// RNE fp32x2 -> packed bf16x2 via the HW instruction
__device__ __forceinline__ unsigned pack2(float x, float y) {
  unsigned r;
  asm("v_cvt_pk_bf16_f32 %0, %1, %2" : "=v"(r) : "v"(x), "v"(y));
  return r;
}

// lane i <- lane i-1, whole-wave (v_mov_b32_dpp wave_shr:1). Lane 0 keeps its
// own value - never consumed (l0-masked).
__device__ __forceinline__ float shfl_up1_dpp(float x) {
  int xi = __float_as_int(x);
  int r = __builtin_amdgcn_update_dpp(xi, xi, 0x138, 0xF, 0xF, false);  // wave_shr:1
  return __int_as_float(r);
}

// quad_perm [1,1,3,3] (code 0xF5): even lanes receive odd neighbor's value
__device__ __forceinline__ float dpp_odd(float x) {
  int xi = __float_as_int(x);
  int r = __builtin_amdgcn_update_dpp(xi, xi, 0xF5, 0xF, 0xF, false);
  return __int_as_float(r);
}

// 3-input min in one VOP3
__device__ __forceinline__ float min3f(float a, float b, float c) {
  float r;
  asm("v_min3_f32 %0, %1, %2, %3" : "=v"(r) : "v"(a), "v"(b), "v"(c));
  return r;
}

// one wave per row of 128 floats; nrm[wid] = sum of squares
__global__ void norm_kernel(const float* __restrict__ s1, const float* __restrict__ s2,
                            float* __restrict__ nrm) {
  int gt   = blockIdx.x * blockDim.x + threadIdx.x;
  int wid  = gt >> 6;
  int lane = gt & 63;
  const float* src = (wid < B_ * L_) ? (s1 + (size_t)wid * F_)
                                     : (s2 + (size_t)(wid - B_ * L_) * F_);
  float2 v = ((const float2*)src)[lane];
  float s = v.x * v.x + v.y * v.y;
#pragma unroll
  for (int o = 32; o > 0; o >>= 1) s += __shfl_xor(s, o, 64);
  if (lane == 0) nrm[wid] = s;
}

// cost matrix -> bf16, two PAIR-skewed streams per batch:
// element (r,c): w = r>>9, rl = r&511; stored at
//   stream[(b*2+w)][u = (c>>1) + (rl>>3)][slot = rl*2 + (c&1)]
// (u-row = 1024 ushorts = 2KB; lane l's slice = 16 ushorts = 32B at slot 16l:
//  8 rows x 2 cols interleaved [r0c0,r0c1,r1c0,r1c1,...]; u = t uniform/wave).
__global__ __launch_bounds__(256) void cost_kernel(const float* __restrict__ s1,
                                                   const float* __restrict__ s2,
                                                   ushort* __restrict__ stream,
                                                   const float* __restrict__ nrm) {
  __shared__ __align__(16) ushort sbuf[2 * 128 * 136];  // aL+bL, reused as stage
  __shared__ float q1[128], q2[128];
  short (*aL)[136] = (short(*)[136])sbuf;
  short (*bL)[136] = (short(*)[136])(sbuf + 128 * 136);
  ushort (*stage)[256] = (ushort(*)[256])sbuf;  // rows 0..79 used (40KB < 68KB)

  const int tid = threadIdx.x;
  const int b   = blockIdx.y;
  const int tc  = blockIdx.x & 7;
  const int tr  = blockIdx.x >> 3;

  const float* Ap = s1 + (size_t)b * L_ * F_ + (size_t)tr * 128 * F_;
  const float* Bp = s2 + (size_t)b * L_ * F_ + (size_t)tc * 128 * F_;

#pragma unroll 4
  for (int it = 0; it < 16; ++it) {
    int idx = it * 1024 + tid * 4;
    int r = idx >> 7, cc = idx & 127;
    float4 va = *(const float4*)(Ap + idx);
    float4 vb = *(const float4*)(Bp + idx);
    *(uint2*)&aL[r][cc] = make_uint2(pack2(va.x, va.y), pack2(va.z, va.w));
    *(uint2*)&bL[r][cc] = make_uint2(pack2(vb.x, vb.y), pack2(vb.z, vb.w));
  }
  if (tid < 128) q1[tid] = nrm[(size_t)b * L_ + tr * 128 + tid];
  else           q2[tid - 128] = nrm[(size_t)B_ * L_ + (size_t)b * L_ + tc * 128 + (tid - 128)];
  __syncthreads();

  const int wave = tid >> 6, lane = tid & 63, quad = lane >> 4, l16 = lane & 15;
  const int m0 = (wave >> 1) * 64, n0 = (wave & 1) * 64;

  f32x4 acc[4][4] = {};
#pragma unroll
  for (int kc = 0; kc < 4; ++kc) {
    short8 af[4], bf[4];
#pragma unroll
    for (int mi = 0; mi < 4; ++mi)
      af[mi] = *(const short8*)&aL[m0 + mi * 16 + l16][kc * 32 + quad * 8];
#pragma unroll
    for (int nj = 0; nj < 4; ++nj)
      bf[nj] = *(const short8*)&bL[n0 + nj * 16 + l16][kc * 32 + quad * 8];
#pragma unroll
    for (int mi = 0; mi < 4; ++mi)
#pragma unroll
      for (int nj = 0; nj < 4; ++nj)
        acc[mi][nj] = __builtin_amdgcn_mfma_f32_16x16x32_bf16(af[mi], bf[nj], acc[mi][nj], 0, 0, 0);
  }

  __syncthreads();  // all waves done reading aL/bL -> safe to reuse as stage

  // epilogue: sqrt-cost -> bf16 pairs, staged at local pair-skew layout.
  // lc parity == l16 parity; even lane merges odd neighbor via quad_perm DPP
  // and writes one uint4 (4 rows x 2 cols interleaved).
#pragma unroll
  for (int mi = 0; mi < 4; ++mi) {
    int lr0 = m0 + mi * 16 + quad * 4;  // 4-aligned; lr0>>3 const over 4 rows
    float a0 = q1[lr0 + 0], a1 = q1[lr0 + 1], a2 = q1[lr0 + 2], a3 = q1[lr0 + 3];
#pragma unroll
    for (int nj = 0; nj < 4; ++nj) {
      int lc = n0 + nj * 16 + l16;
      float qc = q2[lc];
      float v0 = sqrtf(fmaxf(a0 + qc - 2.0f * acc[mi][nj][0], 0.0f));
      float v1 = sqrtf(fmaxf(a1 + qc - 2.0f * acc[mi][nj][1], 0.0f));
      float v2 = sqrtf(fmaxf(a2 + qc - 2.0f * acc[mi][nj][2], 0.0f));
      float v3 = sqrtf(fmaxf(a3 + qc - 2.0f * acc[mi][nj][3], 0.0f));
      float o0 = dpp_odd(v0), o1 = dpp_odd(v1), o2 = dpp_odd(v2), o3 = dpp_odd(v3);
      if ((l16 & 1) == 0) {
        int u = (lr0 >> 3) + (lc >> 1);
        uint4 wd = make_uint4(pack2(v0, o0), pack2(v1, o1), pack2(v2, o2), pack2(v3, o3));
        *(uint4*)&stage[u][lr0 * 2] = wd;  // slots lr0*2..+7; 16B-aligned (lr0%4==0)
      }
    }
  }
  __syncthreads();

  // coalesced write-out: u-row uloc (0..79) -> global u-row ubase+uloc,
  // slot run slotbase..+255 (512B). chunk g = lr>>3 covers slots [16g,16g+16);
  // valid iff lc>>1 = uloc-g in [0,64). Disjoint/covering across blocks:
  // (U,G) determines tr&3=G>>4, g=G&15, p-part U-G -> unique tc.
  const int w        = tr >> 2;
  const int slotbase = 256 * (tr & 3);
  const int ubase    = tc * 64 + 16 * (tr & 3);
  ushort* Sb = stream + ((size_t)(b * 2 + w) * UD2_ + ubase) * 1024 + slotbase;
#pragma unroll
  for (int it = 0; it < 10; ++it) {
    int t = it * 256 + tid;
    if (t < 80 * 32) {
      int u = t >> 5, h = t & 31, g = h >> 1;
      if ((unsigned)(u - g) < 64u)
        *(uint4*)(Sb + (size_t)u * 1024 + g * 16 + (h & 1) * 8) =
            *(const uint4*)&stage[u][g * 16 + (h & 1) * 8];
    }
  }
}

// unpack interleaved pair words + two-column chain.
// col c0: heads/deps h0 = c0head + min3(dg0, up0, left[0]); rows via left[].
// col c1: head = c1head + min3(up0 /*diag1*/, up1, nlA[0]); rows via nlA[].
#define PAIR_STEP(C0HEAD, C1HEAD)                                   \
  {                                                                 \
    unsigned wds[8] = {cwA.x, cwA.y, cwA.z, cwA.w,                  \
                       cwB.x, cwB.y, cwB.z, cwB.w};                 \
    float cv0[8], cv1[8];                                           \
    _Pragma("unroll") for (int r = 0; r < 8; ++r) {                 \
      cv0[r] = __uint_as_float(wds[r] << 16);                       \
      cv1[r] = __uint_as_float(wds[r] & 0xFFFF0000u);               \
    }                                                               \
    float nlA[8], nlB[8];                                           \
    float curA = (C0HEAD) + min3f(dg0, up0, left[0]);               \
    nlA[0] = curA;                                                  \
    _Pragma("unroll") for (int r = 1; r < 8; ++r) {                 \
      curA = cv0[r] + min3f(left[r - 1], left[r], curA);            \
      nlA[r] = curA;                                                \
    }                                                               \
    float curB = (C1HEAD) + min3f(up0, up1, nlA[0]);                \
    nlB[0] = curB;                                                  \
    _Pragma("unroll") for (int r = 1; r < 8; ++r) {                 \
      curB = cv1[r] + min3f(nlA[r - 1], nlA[r], curB);              \
      nlB[r] = curB;                                                \
    }                                                               \
    _Pragma("unroll") for (int r = 0; r < 8; ++r) left[r] = nlB[r]; \
    bot0 = nlA[7]; bot1 = nlB[7];                                   \
  }

// v10: pair-stepping - 2 columns per step, 576 serial steps (vs 1152).
// Amortizes the measured fixed per-step cost (~124cy issue + ~107cy stall,
// invariant across v3-v9) over 2x cells. Pair cross-lane algebra:
//   shA = dpp(bot1), shB = dpp(bot0) at step start (prev step's bots);
//   up0 = shB, up1 = shA, diag1 = up0, diag0 = shA of previous step.
// No sh[] ring. Wave1 lane0: float2 hand[2t..2t+1]; diag0 = prev hCur.y.
// Phases of 16 pair-steps (32 cols = same cols/phase as v9); LAGP=96:
// published <= 32n-127, consumed <= 32n-153 (margin 26). Fast: tBase in
// [64,496]. result = bot1 at t=574. Masking/tail exposure classes verbatim
// the hardware-validated v3-v9 patterns.
__global__ __launch_bounds__(128, 1) void dtw_kernel(const ushort* __restrict__ stream,
                                                     float* __restrict__ out) {
  __shared__ float hand[1040];

  const int b    = blockIdx.x;
  const int tid  = threadIdx.x;
  const int wave = tid >> 6;
  const int lane = tid & 63;
  const bool l0 = (lane == 0);

  const ushort* src = stream + (size_t)(b * 2 + wave) * UD2_ * 1024 + lane * 16;

  float left[8];
#pragma unroll
  for (int r = 0; r < 8; ++r) left[r] = BIGV;
  float bot0 = BIGV, bot1 = BIGV;
  float shAprev = BIGV, hPv = BIGV, result = 0.0f;
  float2 hR[4];
  float hb0[16], hb1[16];
  uint4 pre0[16], pre1[16];

#pragma unroll
  for (int i = 0; i < 16; ++i) {
    pre0[i] = *(const uint4*)(src + (size_t)i * 1024);
    pre1[i] = *(const uint4*)(src + (size_t)i * 1024 + 8);
  }

  for (int n = 0; n < NSEGP_; ++n) {
    __syncthreads();
    const int tBase = 16 * n - (wave ? LAGP_ : 0);
    if ((unsigned)tBase >= 576u) continue;

    const bool fast = (tBase >= 64) & (tBase <= 496);

    if (wave == 0) {
      if (fast) {
#pragma unroll
        for (int k = 0; k < 16; ++k) {
          float shA = shfl_up1_dpp(bot1);
          float shB = shfl_up1_dpp(bot0);
          uint4 cwA = pre0[k], cwB = pre1[k];
          const ushort* p = src + (size_t)(tBase + k + 16) * 1024;  // <= 527 < UD2_
          pre0[k] = *(const uint4*)p;
          pre1[k] = *(const uint4*)(p + 8);
          float dg0 = l0 ? BIGV : shAprev;
          float up0 = l0 ? BIGV : shB;
          float up1 = l0 ? BIGV : shA;
          PAIR_STEP(cv0[0], cv1[0])
          shAprev = shA;
          hb0[k] = bot0; hb1[k] = bot1;
        }
        if (lane == 63) {  // cols 2*tBase-126 .. +31 (all valid in fast window)
          float2* hp = (float2*)&hand[2 * tBase - 126];
#pragma unroll
          for (int q = 0; q < 16; ++q) hp[q] = make_float2(hb0[q], hb1[q]);
        }
      } else {
#pragma unroll
        for (int k = 0; k < 16; ++k) {
          const int t = tBase + k;
          float shA = shfl_up1_dpp(bot1);
          float shB = shfl_up1_dpp(bot0);
          uint4 cwA = pre0[k], cwB = pre1[k];
          const ushort* p = src + (size_t)(tBase + k + 16) * 1024;  // <= 591 < UD2_
          pre0[k] = *(const uint4*)p;
          pre1[k] = *(const uint4*)(p + 8);
          float dg0 = l0 ? ((t == 0) ? 0.0f : BIGV) : shAprev;
          float up0 = l0 ? BIGV : shB;
          float up1 = l0 ? BIGV : shA;
          bool act = ((unsigned)(t - lane) < 512u);
          PAIR_STEP(act ? cv0[0] : BIGV, act ? cv1[0] : BIGV)
          shAprev = shA;
          int j = 2 * t - 126;
          if (lane == 63 && (unsigned)j < 1024u) {
            hand[j] = bot0; hand[j + 1] = bot1;
          }
        }
      }
    } else {
      if (fast) {
#pragma unroll
        for (int i = 0; i < 4; ++i) hR[i] = *(const float2*)&hand[2 * (tBase + i)];
#pragma unroll
        for (int k = 0; k < 16; ++k) {
          float shA = shfl_up1_dpp(bot1);
          float shB = shfl_up1_dpp(bot0);
          float2 hCur = hR[k & 3];
          uint4 cwA = pre0[k], cwB = pre1[k];
          const ushort* p = src + (size_t)(tBase + k + 16) * 1024;
          pre0[k] = *(const uint4*)p;
          pre1[k] = *(const uint4*)(p + 8);
          hR[k & 3] = *(const float2*)&hand[2 * (tBase + k + 4)];  // idx <= 1031 < 1040
          float dg0 = l0 ? hPv : shAprev;
          float up0 = l0 ? hCur.x : shB;
          float up1 = l0 ? hCur.y : shA;
          PAIR_STEP(cv0[0], cv1[0])
          shAprev = shA;
          hPv = hCur.y;
        }
      } else {
#pragma unroll
        for (int i = 0; i < 4; ++i)
          hR[i] = *(const float2*)&hand[(2 * (tBase + i)) & 1023];
#pragma unroll
        for (int k = 0; k < 16; ++k) {
          const int t = tBase + k;
          float shA = shfl_up1_dpp(bot1);
          float shB = shfl_up1_dpp(bot0);
          float2 hCur = hR[k & 3];
          uint4 cwA = pre0[k], cwB = pre1[k];
          const ushort* p = src + (size_t)(tBase + k + 16) * 1024;
          pre0[k] = *(const uint4*)p;
          pre1[k] = *(const uint4*)(p + 8);
          hR[k & 3] = *(const float2*)&hand[(2 * (t + 4)) & 1023];
          float dg0 = l0 ? hPv : shAprev;   // hPv starts BIGV (t==0 boundary)
          float up0 = l0 ? hCur.x : shB;
          float up1 = l0 ? hCur.y : shA;
          bool act = ((unsigned)(t - lane) < 512u);
          PAIR_STEP(act ? cv0[0] : BIGV, act ? cv1[0] : BIGV)
          shAprev = shA;
          hPv = hCur.y;
          if (t == 574) result = bot1;  // lane63 col 1023: D[1024][1024]
        }
      }
    }
  }
  if (wave == 1 && lane == 63) out[b] = 1.0f / (1.0f + result * (1.0f / 2048.0f));
}

extern "C" void kernel_launch(void* const* d_in, const int* in_sizes, int n_in,
                              void* d_out, int out_size, void* d_ws, size_t ws_size,
                              hipStream_t stream_) {
  const float* s1 = (const float*)d_in[0];
  const float* s2 = (const float*)d_in[1];
  float* out = (float*)d_out;
  ushort* cws = (ushort*)d_ws;
  float* nrm = (float*)(cws + STREAM_US);

  norm_kernel<<<dim3((2 * B_ * L_) / 4), 256, 0, stream_>>>(s1, s2, nrm);
  cost_kernel<<<dim3(64, B_), 256, 0, stream_>>>(s1, s2, cws, nrm);
  dtw_kernel<<<dim3(B_), 128, 0, stream_>>>(cws, out);
}

// Round 14
// 211.794 us; speedup vs baseline: 1.3617x; 1.0547x over previous
//
#include <hip/hip_runtime.h>
#include <hip/hip_bf16.h>

#define BIGV 1.0e9f

static constexpr int B_ = 32;
static constexpr int L_ = 1024;
static constexpr int F_ = 128;
static constexpr int UD2_ = 592;      // skewed u-rows per stream (574 used + prefetch slack)
static constexpr int LAGP_ = 96;      // wave1 lag in pair-steps (6 phases of 16; margin 26 cols)
static constexpr int NSEGP_ = 42;     // phases: 36 + 6
static constexpr size_t STREAM_US = (size_t)B_ * 2 * UD2_ * 1024;  // ushorts (77.6 MB)

typedef __attribute__((ext_vector_type(8))) short short8;
typedef __attribute__((ext_vector_type(4))) float f32x4;

// RNE fp32x2 -> packed bf16x2 via the HW instruction
__device__ __forceinline__ unsigned pack2(float x, float y) {
  unsigned r;
  asm("v_cvt_pk_bf16_f32 %0, %1, %2" : "=v"(r) : "v"(x), "v"(y));
  return r;
}

// lane i <- lane i-1, whole-wave (v_mov_b32_dpp wave_shr:1). Lane 0 keeps its
// own value - never consumed (l0-masked).
__device__ __forceinline__ float shfl_up1_dpp(float x) {
  int xi = __float_as_int(x);
  int r = __builtin_amdgcn_update_dpp(xi, xi, 0x138, 0xF, 0xF, false);  // wave_shr:1
  return __int_as_float(r);
}

// quad_perm [1,1,3,3] (code 0xF5): even lanes receive odd neighbor's value
__device__ __forceinline__ float dpp_odd(float x) {
  int xi = __float_as_int(x);
  int r = __builtin_amdgcn_update_dpp(xi, xi, 0xF5, 0xF, 0xF, false);
  return __int_as_float(r);
}

// 3-input min in one VOP3
__device__ __forceinline__ float min3f(float a, float b, float c) {
  float r;
  asm("v_min3_f32 %0, %1, %2, %3" : "=v"(r) : "v"(a), "v"(b), "v"(c));
  return r;
}

// raw v_sqrt_f32 (1 inst vs libm's ~10-inst checked sequence; 1-2ulp f32
// error vanishes under the subsequent bf16 rounding)
__device__ __forceinline__ float fsqrt(float x) {
  float r;
  asm("v_sqrt_f32 %0, %1" : "=v"(r) : "v"(x));
  return r;
}

// one wave per row of 128 floats; nrm[wid] = sum of squares
__global__ void norm_kernel(const float* __restrict__ s1, const float* __restrict__ s2,
                            float* __restrict__ nrm) {
  int gt   = blockIdx.x * blockDim.x + threadIdx.x;
  int wid  = gt >> 6;
  int lane = gt & 63;
  const float* src = (wid < B_ * L_) ? (s1 + (size_t)wid * F_)
                                     : (s2 + (size_t)(wid - B_ * L_) * F_);
  float2 v = ((const float2*)src)[lane];
  float s = v.x * v.x + v.y * v.y;
#pragma unroll
  for (int o = 32; o > 0; o >>= 1) s += __shfl_xor(s, o, 64);
  if (lane == 0) nrm[wid] = s;
}

// cost matrix -> bf16, two PAIR-skewed streams per batch:
// element (r,c): w = r>>9, rl = r&511; stored at
//   stream[(b*2+w)][u = (c>>1) + (rl>>3)][slot = rl*2 + (c&1)]
//
// v11: 8 waves/block (512 thr). Wave w: rows m0=(w&3)*32, cols n0=(w>>2)*64
// -> 32x64 subtile, 2x4 acc quads, 32 MFMAs (half of v10's per-wave serial
// path); staging 8 iters/thread; 16 waves/CU (2 blocks) for latency hiding.
__global__ __launch_bounds__(512) void cost_kernel(const float* __restrict__ s1,
                                                   const float* __restrict__ s2,
                                                   ushort* __restrict__ stream,
                                                   const float* __restrict__ nrm) {
  __shared__ __align__(16) ushort sbuf[2 * 128 * 136];  // aL+bL, reused as stage
  __shared__ float q1[128], q2[128];
  short (*aL)[136] = (short(*)[136])sbuf;
  short (*bL)[136] = (short(*)[136])(sbuf + 128 * 136);
  ushort (*stage)[256] = (ushort(*)[256])sbuf;  // rows 0..79 used (40KB < 68KB)

  const int tid = threadIdx.x;
  const int b   = blockIdx.y;
  const int tc  = blockIdx.x & 7;
  const int tr  = blockIdx.x >> 3;

  const float* Ap = s1 + (size_t)b * L_ * F_ + (size_t)tr * 128 * F_;
  const float* Bp = s2 + (size_t)b * L_ * F_ + (size_t)tc * 128 * F_;

#pragma unroll 4
  for (int it = 0; it < 8; ++it) {
    int idx = it * 2048 + tid * 4;
    int r = idx >> 7, cc = idx & 127;
    float4 va = *(const float4*)(Ap + idx);
    float4 vb = *(const float4*)(Bp + idx);
    *(uint2*)&aL[r][cc] = make_uint2(pack2(va.x, va.y), pack2(va.z, va.w));
    *(uint2*)&bL[r][cc] = make_uint2(pack2(vb.x, vb.y), pack2(vb.z, vb.w));
  }
  if (tid < 128) q1[tid] = nrm[(size_t)b * L_ + tr * 128 + tid];
  else if (tid < 256) q2[tid - 128] = nrm[(size_t)B_ * L_ + (size_t)b * L_ + tc * 128 + (tid - 128)];
  __syncthreads();

  const int wave = tid >> 6, lane = tid & 63, quad = lane >> 4, l16 = lane & 15;
  const int m0 = (wave & 3) * 32, n0 = (wave >> 2) * 64;

  f32x4 acc[2][4] = {};
#pragma unroll
  for (int kc = 0; kc < 4; ++kc) {
    short8 af[2], bf[4];
#pragma unroll
    for (int mi = 0; mi < 2; ++mi)
      af[mi] = *(const short8*)&aL[m0 + mi * 16 + l16][kc * 32 + quad * 8];
#pragma unroll
    for (int nj = 0; nj < 4; ++nj)
      bf[nj] = *(const short8*)&bL[n0 + nj * 16 + l16][kc * 32 + quad * 8];
#pragma unroll
    for (int mi = 0; mi < 2; ++mi)
#pragma unroll
      for (int nj = 0; nj < 4; ++nj)
        acc[mi][nj] = __builtin_amdgcn_mfma_f32_16x16x32_bf16(af[mi], bf[nj], acc[mi][nj], 0, 0, 0);
  }

  __syncthreads();  // all waves done reading aL/bL -> safe to reuse as stage

  // epilogue: sqrt-cost -> bf16 pairs, staged at local pair-skew layout.
  // lc parity == l16 parity; even lane merges odd neighbor via quad_perm DPP
  // and writes one uint4 (4 rows x 2 cols interleaved).
#pragma unroll
  for (int mi = 0; mi < 2; ++mi) {
    int lr0 = m0 + mi * 16 + quad * 4;  // 4-aligned; lr0>>3 const over 4 rows
    float a0 = q1[lr0 + 0], a1 = q1[lr0 + 1], a2 = q1[lr0 + 2], a3 = q1[lr0 + 3];
#pragma unroll
    for (int nj = 0; nj < 4; ++nj) {
      int lc = n0 + nj * 16 + l16;
      float qc = q2[lc];
      float v0 = fsqrt(fmaxf(a0 + qc - 2.0f * acc[mi][nj][0], 0.0f));
      float v1 = fsqrt(fmaxf(a1 + qc - 2.0f * acc[mi][nj][1], 0.0f));
      float v2 = fsqrt(fmaxf(a2 + qc - 2.0f * acc[mi][nj][2], 0.0f));
      float v3 = fsqrt(fmaxf(a3 + qc - 2.0f * acc[mi][nj][3], 0.0f));
      float o0 = dpp_odd(v0), o1 = dpp_odd(v1), o2 = dpp_odd(v2), o3 = dpp_odd(v3);
      if ((l16 & 1) == 0) {
        int u = (lr0 >> 3) + (lc >> 1);   // <= 15 + 63 = 78 < 80
        uint4 wd = make_uint4(pack2(v0, o0), pack2(v1, o1), pack2(v2, o2), pack2(v3, o3));
        *(uint4*)&stage[u][lr0 * 2] = wd;  // slots lr0*2..+7; 16B-aligned (lr0%4==0)
      }
    }
  }
  __syncthreads();

  // coalesced write-out: u-row uloc (0..79) -> global u-row ubase+uloc,
  // slot run slotbase..+255 (512B). chunk g covers slots [16g,16g+16);
  // valid iff lc>>1 = uloc-g in [0,64).
  const int w        = tr >> 2;
  const int slotbase = 256 * (tr & 3);
  const int ubase    = tc * 64 + 16 * (tr & 3);
  ushort* Sb = stream + ((size_t)(b * 2 + w) * UD2_ + ubase) * 1024 + slotbase;
#pragma unroll
  for (int it = 0; it < 5; ++it) {
    int t = it * 512 + tid;
    if (t < 80 * 32) {
      int u = t >> 5, h = t & 31, g = h >> 1;
      if ((unsigned)(u - g) < 64u)
        *(uint4*)(Sb + (size_t)u * 1024 + g * 16 + (h & 1) * 8) =
            *(const uint4*)&stage[u][g * 16 + (h & 1) * 8];
    }
  }
}

// unpack interleaved pair words + two-column chain.
#define PAIR_STEP(C0HEAD, C1HEAD)                                   \
  {                                                                 \
    unsigned wds[8] = {cwA.x, cwA.y, cwA.z, cwA.w,                  \
                       cwB.x, cwB.y, cwB.z, cwB.w};                 \
    float cv0[8], cv1[8];                                           \
    _Pragma("unroll") for (int r = 0; r < 8; ++r) {                 \
      cv0[r] = __uint_as_float(wds[r] << 16);                       \
      cv1[r] = __uint_as_float(wds[r] & 0xFFFF0000u);               \
    }                                                               \
    float nlA[8], nlB[8];                                           \
    float curA = (C0HEAD) + min3f(dg0, up0, left[0]);               \
    nlA[0] = curA;                                                  \
    _Pragma("unroll") for (int r = 1; r < 8; ++r) {                 \
      curA = cv0[r] + min3f(left[r - 1], left[r], curA);            \
      nlA[r] = curA;                                                \
    }                                                               \
    float curB = (C1HEAD) + min3f(up0, up1, nlA[0]);                \
    nlB[0] = curB;                                                  \
    _Pragma("unroll") for (int r = 1; r < 8; ++r) {                 \
      curB = cv1[r] + min3f(nlA[r - 1], nlA[r], curB);              \
      nlB[r] = curB;                                                \
    }                                                               \
    _Pragma("unroll") for (int r = 0; r < 8; ++r) left[r] = nlB[r]; \
    bot0 = nlA[7]; bot1 = nlB[7];                                   \
  }

// v10 dtw (measured 103us): pair-stepping - 2 columns per step, 576 serial
// steps. shA = dpp(bot1), shB = dpp(bot0); up0 = shB, up1 = shA,
// diag1 = up0, diag0 = prev shA. Wave1 lane0: float2 hand[2t..2t+1].
// Phases of 16 pair-steps; LAGP=96 (margin 26). Fast: tBase in [64,496].
__global__ __launch_bounds__(128, 1) void dtw_kernel(const ushort* __restrict__ stream,
                                                     float* __restrict__ out) {
  __shared__ float hand[1040];

  const int b    = blockIdx.x;
  const int tid  = threadIdx.x;
  const int wave = tid >> 6;
  const int lane = tid & 63;
  const bool l0 = (lane == 0);

  const ushort* src = stream + (size_t)(b * 2 + wave) * UD2_ * 1024 + lane * 16;

  float left[8];
#pragma unroll
  for (int r = 0; r < 8; ++r) left[r] = BIGV;
  float bot0 = BIGV, bot1 = BIGV;
  float shAprev = BIGV, hPv = BIGV, result = 0.0f;
  float2 hR[4];
  float hb0[16], hb1[16];
  uint4 pre0[16], pre1[16];

#pragma unroll
  for (int i = 0; i < 16; ++i) {
    pre0[i] = *(const uint4*)(src + (size_t)i * 1024);
    pre1[i] = *(const uint4*)(src + (size_t)i * 1024 + 8);
  }

  for (int n = 0; n < NSEGP_; ++n) {
    __syncthreads();
    const int tBase = 16 * n - (wave ? LAGP_ : 0);
    if ((unsigned)tBase >= 576u) continue;

    const bool fast = (tBase >= 64) & (tBase <= 496);

    if (wave == 0) {
      if (fast) {
#pragma unroll
        for (int k = 0; k < 16; ++k) {
          float shA = shfl_up1_dpp(bot1);
          float shB = shfl_up1_dpp(bot0);
          uint4 cwA = pre0[k], cwB = pre1[k];
          const ushort* p = src + (size_t)(tBase + k + 16) * 1024;  // <= 527 < UD2_
          pre0[k] = *(const uint4*)p;
          pre1[k] = *(const uint4*)(p + 8);
          float dg0 = l0 ? BIGV : shAprev;
          float up0 = l0 ? BIGV : shB;
          float up1 = l0 ? BIGV : shA;
          PAIR_STEP(cv0[0], cv1[0])
          shAprev = shA;
          hb0[k] = bot0; hb1[k] = bot1;
        }
        if (lane == 63) {  // cols 2*tBase-126 .. +31 (all valid in fast window)
          float2* hp = (float2*)&hand[2 * tBase - 126];
#pragma unroll
          for (int q = 0; q < 16; ++q) hp[q] = make_float2(hb0[q], hb1[q]);
        }
      } else {
#pragma unroll
        for (int k = 0; k < 16; ++k) {
          const int t = tBase + k;
          float shA = shfl_up1_dpp(bot1);
          float shB = shfl_up1_dpp(bot0);
          uint4 cwA = pre0[k], cwB = pre1[k];
          const ushort* p = src + (size_t)(tBase + k + 16) * 1024;  // <= 591 < UD2_
          pre0[k] = *(const uint4*)p;
          pre1[k] = *(const uint4*)(p + 8);
          float dg0 = l0 ? ((t == 0) ? 0.0f : BIGV) : shAprev;
          float up0 = l0 ? BIGV : shB;
          float up1 = l0 ? BIGV : shA;
          bool act = ((unsigned)(t - lane) < 512u);
          PAIR_STEP(act ? cv0[0] : BIGV, act ? cv1[0] : BIGV)
          shAprev = shA;
          int j = 2 * t - 126;
          if (lane == 63 && (unsigned)j < 1024u) {
            hand[j] = bot0; hand[j + 1] = bot1;
          }
        }
      }
    } else {
      if (fast) {
#pragma unroll
        for (int i = 0; i < 4; ++i) hR[i] = *(const float2*)&hand[2 * (tBase + i)];
#pragma unroll
        for (int k = 0; k < 16; ++k) {
          float shA = shfl_up1_dpp(bot1);
          float shB = shfl_up1_dpp(bot0);
          float2 hCur = hR[k & 3];
          uint4 cwA = pre0[k], cwB = pre1[k];
          const ushort* p = src + (size_t)(tBase + k + 16) * 1024;
          pre0[k] = *(const uint4*)p;
          pre1[k] = *(const uint4*)(p + 8);
          hR[k & 3] = *(const float2*)&hand[2 * (tBase + k + 4)];  // idx <= 1031 < 1040
          float dg0 = l0 ? hPv : shAprev;
          float up0 = l0 ? hCur.x : shB;
          float up1 = l0 ? hCur.y : shA;
          PAIR_STEP(cv0[0], cv1[0])
          shAprev = shA;
          hPv = hCur.y;
        }
      } else {
#pragma unroll
        for (int i = 0; i < 4; ++i)
          hR[i] = *(const float2*)&hand[(2 * (tBase + i)) & 1023];
#pragma unroll
        for (int k = 0; k < 16; ++k) {
          const int t = tBase + k;
          float shA = shfl_up1_dpp(bot1);
          float shB = shfl_up1_dpp(bot0);
          float2 hCur = hR[k & 3];
          uint4 cwA = pre0[k], cwB = pre1[k];
          const ushort* p = src + (size_t)(tBase + k + 16) * 1024;
          pre0[k] = *(const uint4*)p;
          pre1[k] = *(const uint4*)(p + 8);
          hR[k & 3] = *(const float2*)&hand[(2 * (t + 4)) & 1023];
          float dg0 = l0 ? hPv : shAprev;   // hPv starts BIGV (t==0 boundary)
          float up0 = l0 ? hCur.x : shB;
          float up1 = l0 ? hCur.y : shA;
          bool act = ((unsigned)(t - lane) < 512u);
          PAIR_STEP(act ? cv0[0] : BIGV, act ? cv1[0] : BIGV)
          shAprev = shA;
          hPv = hCur.y;
          if (t == 574) result = bot1;  // lane63 col 1023: D[1024][1024]
        }
      }
    }
  }
  if (wave == 1 && lane == 63) out[b] = 1.0f / (1.0f + result * (1.0f / 2048.0f));
}

extern "C" void kernel_launch(void* const* d_in, const int* in_sizes, int n_in,
                              void* d_out, int out_size, void* d_ws, size_t ws_size,
                              hipStream_t stream_) {
  const float* s1 = (const float*)d_in[0];
  const float* s2 = (const float*)d_in[1];
  float* out = (float*)d_out;
  ushort* cws = (ushort*)d_ws;
  float* nrm = (float*)(cws + STREAM_US);

  norm_kernel<<<dim3((2 * B_ * L_) / 4), 256, 0, stream_>>>(s1, s2, nrm);
  cost_kernel<<<dim3(64, B_), 512, 0, stream_>>>(s1, s2, cws, nrm);
  dtw_kernel<<<dim3(B_), 128, 0, stream_>>>(cws, out);
}